// Round 3
// baseline (973.886 us; speedup 1.0000x reference)
//
#include <hip/hip_runtime.h>
#include <hip/hip_bf16.h>

#define N_ROWS 32768
#define DQ 512
#define DC 2048
#define KDIM 2048

typedef float f32x4 __attribute__((ext_vector_type(4)));
typedef short bf16x8 __attribute__((ext_vector_type(8)));

// ---------------------------------------------------------------------------
// Pack W_block [2048,2048] row-major bf16: W_blk[o][i] = sgn(ob,ib) * W_{ob^ib}[o&511][i&511]
// sign mask bit (ob*4+ib): negative. Verified vs reference Hamilton rows:
//  ob0: +r -i -j -k | ob1: +i +r +k -j | ob2: +j -k +r +i | ob3: +k +j -i +r
// ---------------------------------------------------------------------------
__global__ void pack_w_kernel(const float* __restrict__ Wr, const float* __restrict__ Wi,
                              const float* __restrict__ Wj, const float* __restrict__ Wk,
                              __hip_bfloat16* __restrict__ Wblk) {
    int idx = blockIdx.x * blockDim.x + threadIdx.x;   // 2048*2048/4 threads
    int base = idx * 4;
    int o = base >> 11;
    int i = base & 2047;
    int ob = o >> 9, ib = i >> 9;
    int oo = o & 511, ii = i & 511;
    int s = ob ^ ib;
    const float* src = (s == 0) ? Wr : (s == 1) ? Wi : (s == 2) ? Wj : Wk;
    float sgn = ((0x428E >> (ob * 4 + ib)) & 1) ? -1.0f : 1.0f;
    float4 v = *(const float4*)(src + oo * 512 + ii);
    __hip_bfloat16 outv[4];
    outv[0] = __float2bfloat16(sgn * v.x);
    outv[1] = __float2bfloat16(sgn * v.y);
    outv[2] = __float2bfloat16(sgn * v.z);
    outv[3] = __float2bfloat16(sgn * v.w);
    *(uint2*)(Wblk + base) = *(uint2*)outv;
}

__global__ void pack_bias_kernel(const float* __restrict__ b1r, const float* __restrict__ b1i,
                                 const float* __restrict__ b1j, const float* __restrict__ b1k,
                                 const float* __restrict__ b2r, const float* __restrict__ b2i,
                                 const float* __restrict__ b2j, const float* __restrict__ b2k,
                                 float* __restrict__ b1full, float* __restrict__ b2full) {
    int idx = blockIdx.x * blockDim.x + threadIdx.x;   // 2048 threads
    int c = idx >> 9, d = idx & 511;
    const float* s1 = (c == 0) ? b1r : (c == 1) ? b1i : (c == 2) ? b1j : b1k;
    const float* s2 = (c == 0) ? b2r : (c == 1) ? b2i : (c == 2) ? b2j : b2k;
    b1full[idx] = s1[d];
    b2full[idx] = s2[d];
}

// x_cat[n][c*512+d] = q_c[n][d], fp32 -> bf16. 8 elems/thread; one wave spans
// exactly one 512-col component region -> fully coalesced.
__global__ void pack_x_kernel(const float* __restrict__ qr, const float* __restrict__ qi,
                              const float* __restrict__ qj, const float* __restrict__ qk,
                              __hip_bfloat16* __restrict__ xcat) {
    int idx = blockIdx.x * blockDim.x + threadIdx.x;   // N_ROWS*DC/8 threads
    size_t base = (size_t)idx * 8;
    int col = (int)(base & 2047);
    size_t n = base >> 11;
    int c = col >> 9, d = col & 511;
    const float* src = (c == 0) ? qr : (c == 1) ? qi : (c == 2) ? qj : qk;
    const float* p = src + n * 512 + d;
    float4 v0 = *(const float4*)(p);
    float4 v1 = *(const float4*)(p + 4);
    __hip_bfloat16 o[8];
    o[0] = __float2bfloat16(v0.x); o[1] = __float2bfloat16(v0.y);
    o[2] = __float2bfloat16(v0.z); o[3] = __float2bfloat16(v0.w);
    o[4] = __float2bfloat16(v1.x); o[5] = __float2bfloat16(v1.y);
    o[6] = __float2bfloat16(v1.z); o[7] = __float2bfloat16(v1.w);
    *(uint4*)(xcat + base) = *(uint4*)o;
}

// ---------------------------------------------------------------------------
// 256x256-tile BT GEMM: C[M,2048] = A[M,2048] @ B[2048,2048]^T
// 8 waves (2M x 4N), BK=64. BOTH A and B double-buffered as full 256x64
// regions: lds[buf][A|B][256*64] = 128 KiB. ONE barrier + one (cheap)
// vmcnt(0) per K-tile:
//   vmcnt(0)  -- drains own stage(u) loads, issued a full tile (~2400cy) ago
//   s_barrier -- all waves' stage(u) landed; reads of buf b now safe;
//                all waves' reads of buf b^1 (tile u-1) are behind this barrier
//   ks0: reads(af,bf @cbs0) | STAGE A(u+1)->b^1 (HBM-cold, issued early)
//        | 32 MFMA
//   ks1: reads(af,bf @cbs1) | STAGE B(u+1)->b^1 (L2-hot, issued late)
//        | 32 MFMA
// Hazards: stage(u+1 -> b^1) vs reads(b^1 in tile u-1): separated by BAR(u).
//          reads(b) vs stage(u -> b): each wave vmcnt(0)-drains own loads
//          pre-barrier; barrier publishes completion to all waves.
// LDS swizzle: col_byte ^= ((row&7)<<4), applied on the global SOURCE address
// (global_load_lds writes linearly) and on the LDS read offset; row&7 == lane&7
// for both staging (srow) and frag reads (lm), so per-lane XOR is constant.
// MODE 0: C = relu(acc+bias) -> bf16 row-major [M, 2048]
// MODE 1: C = acc+bias -> fp32 scattered into 4 blocks of [M,512] (d_out layout)
// ---------------------------------------------------------------------------
template <int MODE>
__global__ __launch_bounds__(512, 2) void qgemm8_kernel(
    const __hip_bfloat16* __restrict__ A,
    const __hip_bfloat16* __restrict__ B,
    const float* __restrict__ bias,
    void* __restrict__ Cout, int M)
{
    constexpr int NT = KDIM / 64;               // 32 K-tiles
    __shared__ short lds[2][2][16384];          // [buf][A,B][256*64] = 128 KiB

    const int t = threadIdx.x;
    const int lane = t & 63;
    const int wv = t >> 6;
    const int wrow = wv >> 2;                   // 0..1 -> M half (128 rows)
    const int wcol = wv & 3;                    // 0..3 -> N quarter (64 cols)
    const int lm = lane & 15;

    const int m0 = blockIdx.y * 256;
    const int n0 = blockIdx.x * 256;

    const short* Ag = (const short*)A;
    const short* Bg = (const short*)B;

    // per-lane swizzled LDS column offsets (shorts) for ks=0,1
    const int swzb = (lane & 7) << 4;
    const int cbs0 = ((((lane >> 4) << 4)) ^ swzb) >> 1;
    const int cbs1 = ((64 + ((lane >> 4) << 4)) ^ swzb) >> 1;

    // staging geometry: per instr, wave covers 8 rows (8 lanes x 16B per row)
    const int srow = (wv << 3) + (lane >> 3);
    const int secol = ((lane & 7) ^ (lane >> 3)) << 3;   // pre-swizzled source col (elems)

    // stage a full 256x64 region (A or B) with 4 global_load_lds per wave
    auto STAGE4 = [&](const short* G, int grow, int kk, short* region) {
#pragma unroll
        for (int i = 0; i < 4; i++) {
            __builtin_amdgcn_global_load_lds(
                (const __attribute__((address_space(1))) void*)
                    (G + (size_t)(grow + srow + i * 64) * KDIM + kk + secol),
                (__attribute__((address_space(3))) void*)(region + i * 4096 + wv * 512),
                16, 0, 0);
        }
    };

    f32x4 acc[8][4] = {};

    // prologue: stage tile 0 into buf 0 (8 loads outstanding)
    STAGE4(Ag, m0, 0, lds[0][0]);
    STAGE4(Bg, n0, 0, lds[0][1]);

    for (int u = 0; u < NT; ++u) {
        const int b = u & 1;
        const short* aR = lds[b][0];
        const short* bR = lds[b][1];
        const int kk = u * 64;

        asm volatile("s_waitcnt vmcnt(0)" ::: "memory");
        __builtin_amdgcn_s_barrier();

        bf16x8 af[8], bfr[4];

        // ---------------- ks = 0 ----------------
#pragma unroll
        for (int mi = 0; mi < 8; mi++)
            af[mi] = *(const bf16x8*)(aR + (wrow * 128 + mi * 16 + lm) * 64 + cbs0);
#pragma unroll
        for (int ni = 0; ni < 4; ni++)
            bfr[ni] = *(const bf16x8*)(bR + (wcol * 64 + ni * 16 + lm) * 64 + cbs0);
        if (u < NT - 1) STAGE4(Ag, m0, kk + 64, lds[b ^ 1][0]);
        __builtin_amdgcn_s_setprio(1);
#pragma unroll
        for (int mi = 0; mi < 8; mi++)
#pragma unroll
            for (int ni = 0; ni < 4; ni++)
                acc[mi][ni] = __builtin_amdgcn_mfma_f32_16x16x32_bf16(
                    af[mi], bfr[ni], acc[mi][ni], 0, 0, 0);
        __builtin_amdgcn_s_setprio(0);

        // ---------------- ks = 1 ----------------
#pragma unroll
        for (int mi = 0; mi < 8; mi++)
            af[mi] = *(const bf16x8*)(aR + (wrow * 128 + mi * 16 + lm) * 64 + cbs1);
#pragma unroll
        for (int ni = 0; ni < 4; ni++)
            bfr[ni] = *(const bf16x8*)(bR + (wcol * 64 + ni * 16 + lm) * 64 + cbs1);
        if (u < NT - 1) STAGE4(Bg, n0, kk + 64, lds[b ^ 1][1]);
        __builtin_amdgcn_s_setprio(1);
#pragma unroll
        for (int mi = 0; mi < 8; mi++)
#pragma unroll
            for (int ni = 0; ni < 4; ni++)
                acc[mi][ni] = __builtin_amdgcn_mfma_f32_16x16x32_bf16(
                    af[mi], bfr[ni], acc[mi][ni], 0, 0, 0);
        __builtin_amdgcn_s_setprio(0);
    }

    // epilogue: C row = mi8*16 + (lane>>4)*4 + r (+wave/tile offsets), col = lane&15 (+offsets)
#pragma unroll
    for (int mi8 = 0; mi8 < 8; mi8++) {
#pragma unroll
        for (int ni4 = 0; ni4 < 4; ni4++) {
            const int n_g = n0 + wcol * 64 + ni4 * 16 + lm;
            const float bia = bias[n_g];
#pragma unroll
            for (int r = 0; r < 4; r++) {
                const int m_g = m0 + wrow * 128 + mi8 * 16 + (lane >> 4) * 4 + r;
                float v = acc[mi8][ni4][r] + bia;
                if (MODE == 0) {
                    v = fmaxf(v, 0.0f);
                    ((__hip_bfloat16*)Cout)[(size_t)m_g * DC + n_g] = __float2bfloat16(v);
                } else {
                    const int c = n_g >> 9, d = n_g & 511;
                    ((float*)Cout)[(size_t)c * ((size_t)M * DQ) + (size_t)m_g * DQ + d] = v;
                }
            }
        }
    }
}

extern "C" void kernel_launch(void* const* d_in, const int* in_sizes, int n_in,
                              void* d_out, int out_size, void* d_ws, size_t ws_size,
                              hipStream_t stream) {
    const float* qr = (const float*)d_in[0];
    const float* qi = (const float*)d_in[1];
    const float* qj = (const float*)d_in[2];
    const float* qk = (const float*)d_in[3];
    const float* W1r = (const float*)d_in[4];
    const float* W1i = (const float*)d_in[5];
    const float* W1j = (const float*)d_in[6];
    const float* W1k = (const float*)d_in[7];
    const float* W2r = (const float*)d_in[8];
    const float* W2i = (const float*)d_in[9];
    const float* W2j = (const float*)d_in[10];
    const float* W2k = (const float*)d_in[11];
    const float* b1r = (const float*)d_in[12];
    const float* b1i = (const float*)d_in[13];
    const float* b1j = (const float*)d_in[14];
    const float* b1k = (const float*)d_in[15];
    const float* b2r = (const float*)d_in[16];
    const float* b2i = (const float*)d_in[17];
    const float* b2j = (const float*)d_in[18];
    const float* b2k = (const float*)d_in[19];

    char* ws = (char*)d_ws;
    __hip_bfloat16* W1blk = (__hip_bfloat16*)ws;                       // 8 MiB
    __hip_bfloat16* W2blk = (__hip_bfloat16*)(ws + (8u << 20));        // 8 MiB
    float* b1full = (float*)(ws + (16u << 20));                        // 8 KiB
    float* b2full = b1full + 2048;                                     // 8 KiB
    __hip_bfloat16* xcat = (__hip_bfloat16*)(ws + (16u << 20) + 65536); // 128 MiB
    __hip_bfloat16* H = xcat + (size_t)N_ROWS * DC;                    // 128 MiB

    pack_w_kernel<<<(2048 * 2048 / 4) / 256, 256, 0, stream>>>(W1r, W1i, W1j, W1k, W1blk);
    pack_w_kernel<<<(2048 * 2048 / 4) / 256, 256, 0, stream>>>(W2r, W2i, W2j, W2k, W2blk);
    pack_bias_kernel<<<8, 256, 0, stream>>>(b1r, b1i, b1j, b1k, b2r, b2i, b2j, b2k, b1full, b2full);
    pack_x_kernel<<<(N_ROWS * (size_t)DC / 8) / 256, 256, 0, stream>>>(qr, qi, qj, qk, xcat);

    // grid: 8 N-tiles (fastest) x 128 M-tiles. gridDim.x == 8 == #XCDs -> natural
    // round-robin dispatch pins one 1-MB B-panel per XCD L2 while A streams.
    dim3 grid(DC / 256, N_ROWS / 256);
    qgemm8_kernel<0><<<grid, 512, 0, stream>>>(xcat, W1blk, b1full, (void*)H, N_ROWS);
    qgemm8_kernel<1><<<grid, 512, 0, stream>>>(H, W2blk, b2full, d_out, N_ROWS);
}